// Round 5
// baseline (1780.651 us; speedup 1.0000x reference)
//
#include <hip/hip_runtime.h>
#include <hip/hip_bf16.h>

#define DL 6
#define DD 1024
#define DH 16
#define DF 4096
#define DB 2
#define DS 1024
#define DDK 64

typedef __hip_bfloat16 bf16;
typedef short mfma_t;
typedef mfma_t mfma8 __attribute__((ext_vector_type(8)));
typedef float floatx4 __attribute__((ext_vector_type(4)));

__device__ __forceinline__ float b2f(bf16 v) { return __bfloat162float(v); }
__device__ __forceinline__ bf16 f2b(float v) { return __float2bfloat16(v); }
__device__ __forceinline__ float rd(const void* p, size_t i, int dt) {
  return dt ? b2f(((const bf16*)p)[i]) : ((const float*)p)[i];
}

// async global->LDS, 16B per lane; LDS dest = wave-uniform base + lane*16
__device__ __forceinline__ void gld_lds16(const bf16* g, bf16* l) {
  __builtin_amdgcn_global_load_lds(
      (const __attribute__((address_space(1))) unsigned int*)g,
      (__attribute__((address_space(3))) unsigned int*)l, 16, 0, 0);
}

__global__ void detect_dtype(const unsigned* __restrict__ msk, int* __restrict__ flag) {
  if (threadIdx.x == 0) flag[0] = (msk[0] == 0x3F800000u) ? 0 : 1;
}

template <int OP>
__device__ __forceinline__ float block_reduce(float v, float* sm) {
#pragma unroll
  for (int off = 32; off > 0; off >>= 1) {
    float o = __shfl_down(v, off, 64);
    v = OP ? fmaxf(v, o) : v + o;
  }
  if ((threadIdx.x & 63) == 0) sm[threadIdx.x >> 6] = v;
  __syncthreads();
  float r = OP ? fmaxf(fmaxf(sm[0], sm[1]), fmaxf(sm[2], sm[3]))
               : (sm[0] + sm[1]) + (sm[2] + sm[3]);
  __syncthreads();
  return r;
}

__global__ __launch_bounds__(256) void embed_kernel(const int* __restrict__ ids,
                                                    const void* __restrict__ emb,
                                                    const void* __restrict__ pe,
                                                    const int* __restrict__ dflag,
                                                    float* __restrict__ x) {
  const int dt = dflag[0];
  int t = blockIdx.x;
  int id = ids[t];
  int s = t & (DS - 1);
  int c = threadIdx.x * 4;
  float* xo = x + (size_t)t * DD + c;
#pragma unroll
  for (int i = 0; i < 4; ++i)
    xo[i] = rd(emb, (size_t)id * DD + c + i, dt) * 32.0f + rd(pe, (size_t)s * DD + c + i, dt);
}

// s,b indexed at [poff + c]; poff = layer element offset (dtype-independent count)
__global__ __launch_bounds__(256) void ln_kernel(const float* __restrict__ x,
                                                 const void* __restrict__ s,
                                                 const void* __restrict__ b,
                                                 long long poff,
                                                 const int* __restrict__ dflag,
                                                 void* __restrict__ out, int is_final) {
  __shared__ float sm[4];
  const int dt = dflag[0];
  int row = blockIdx.x;
  const float4* xr = (const float4*)(x + (size_t)row * DD);
  float4 v = xr[threadIdx.x];
  float sum = block_reduce<0>(v.x + v.y + v.z + v.w, sm);
  float mean = sum * (1.0f / DD);
  float dx = v.x - mean, dy = v.y - mean, dz = v.z - mean, dw = v.w - mean;
  float ss = block_reduce<0>(dx * dx + dy * dy + dz * dz + dw * dw, sm);
  float rstd = rsqrtf(ss * (1.0f / DD) + 1e-6f);
  int c = threadIdx.x * 4;
  size_t p = (size_t)poff + c;
  float o0 = dx * rstd * rd(s, p + 0, dt) + rd(b, p + 0, dt);
  float o1 = dy * rstd * rd(s, p + 1, dt) + rd(b, p + 1, dt);
  float o2 = dz * rstd * rd(s, p + 2, dt) + rd(b, p + 2, dt);
  float o3 = dw * rstd * rd(s, p + 3, dt) + rd(b, p + 3, dt);
  if (is_final && dt == 0) {
    float* o = (float*)out + (size_t)row * DD + c;
    o[0] = o0; o[1] = o1; o[2] = o2; o[3] = o3;
  } else {
    bf16* o = (bf16*)out + (size_t)row * DD + c;
    o[0] = f2b(o0); o[1] = f2b(o1); o[2] = f2b(o2); o[3] = f2b(o3);
  }
}

// out[cols][rows] = in[roff + r][c] for r in [0,rows), element offset roff rows
__global__ __launch_bounds__(256) void transpose_any(const void* __restrict__ in,
                                                     long long row_off,
                                                     bf16* __restrict__ out,
                                                     int rows, int cols,
                                                     const int* __restrict__ dflag) {
  __shared__ bf16 t[32][33];
  const int dt = dflag[0];
  int c0 = blockIdx.x * 32, r0 = blockIdx.y * 32;
  int tx = threadIdx.x & 31, ty = threadIdx.x >> 5;
#pragma unroll
  for (int i = 0; i < 4; ++i) {
    int r = ty + i * 8;
    size_t idx = (size_t)(row_off + r0 + r) * cols + c0 + tx;
    t[r][tx] = dt ? ((const bf16*)in)[idx] : f2b(((const float*)in)[idx]);
  }
  __syncthreads();
#pragma unroll
  for (int i = 0; i < 4; ++i) {
    int r = ty + i * 8;
    out[(size_t)(c0 + r) * rows + r0 + tx] = t[tx][r];
  }
}

__global__ __launch_bounds__(256) void vtrans_kernel(const bf16* __restrict__ qkv,
                                                     bf16* __restrict__ vt) {
  __shared__ bf16 t[32][33];
  int bh = blockIdx.z;
  const bf16* src = qkv + (size_t)(bh >> 4) * DS * 3072 + 2048 + (bh & 15) * DDK;
  bf16* dst = vt + (size_t)bh * DDK * DS;
  int s0 = blockIdx.x * 32, d0 = blockIdx.y * 32;
  int tx = threadIdx.x & 31, ty = threadIdx.x >> 5;
#pragma unroll
  for (int i = 0; i < 4; ++i) {
    int r = ty + i * 8;
    t[r][tx] = src[(size_t)(s0 + r) * 3072 + d0 + tx];
  }
  __syncthreads();
#pragma unroll
  for (int i = 0; i < 4; ++i) {
    int r = ty + i * 8;
    dst[(size_t)(d0 + r) * DS + s0 + tx] = t[tx][r];
  }
}

// ---------------- fused flash attention ----------------
// grid (DS/64, DB*DH); 4 waves; wave w owns q-rows [w*16, w*16+16).
// Swapped QK^T: S^T tile = mfma(A=K_rows, B=Q_rows) -> lane16 = q, laneq*4+r = k.
// K/Q/V staged via global_load_lds with pre-swizzled SOURCE (XOR (row&7)<<4 on
// 16B slots); ds_read applies the same XOR -> 2-way bank aliasing (free).
#define KVBLK 128
__global__ __launch_bounds__(256) void flash_attn(const bf16* __restrict__ qkv,
                                                  const bf16* __restrict__ vt,
                                                  const void* __restrict__ msk,
                                                  const int* __restrict__ dflag,
                                                  bf16* __restrict__ ao) {
  __shared__ __align__(16) bf16 Qs[64 * 64];         // [q][d]   8 KB
  __shared__ __align__(16) bf16 Ks[KVBLK * 64];      // [k][d]  16 KB
  __shared__ __align__(16) bf16 Vs[64 * KVBLK];      // [d][k]  16 KB (from vt)
  __shared__ __align__(16) bf16 Ps[4 * 16 * KVBLK];  // per-wave P 16 KB
  __shared__ float Ms[KVBLK];
  __shared__ float Sx[4][16];

  const int tid = threadIdx.x;
  const int lane = tid & 63, wave = tid >> 6;
  const int lane16 = lane & 15, laneq = lane >> 4;
  const int dt = dflag[0];
  const int qt = blockIdx.x, bh = blockIdx.y;
  const int b = bh >> 4, h = bh & 15;
  const int q0 = qt * 64;

  const bf16* Qg = qkv + (size_t)b * DS * 3072 + (size_t)q0 * 3072 + h * 64;
  const bf16* Kg = qkv + (size_t)b * DS * 3072 + 1024 + h * 64;
  const bf16* Vg = vt + (size_t)bh * DDK * DS;

  // stage Q once: 64 rows x 8 slots(16B)
#pragma unroll
  for (int i = 0; i < 2; ++i) {
    int c = tid + i * 256;
    int row = c >> 3, sl = c & 7;
    gld_lds16(Qg + (size_t)row * 3072 + ((sl ^ (row & 7)) << 3), &Qs[c * 8]);
  }
  // stage K,V,mask for tile kv0
  auto stage = [&](int kv0) {
#pragma unroll
    for (int i = 0; i < 4; ++i) {
      int c = tid + i * 256;
      int row = c >> 3, sl = c & 7;
      gld_lds16(Kg + (size_t)(kv0 + row) * 3072 + ((sl ^ (row & 7)) << 3), &Ks[c * 8]);
    }
#pragma unroll
    for (int i = 0; i < 4; ++i) {
      int c = tid + i * 256;
      int row = c >> 4, sl = c & 15;
      gld_lds16(Vg + (size_t)row * DS + kv0 + ((sl ^ (row & 7)) << 3), &Vs[c * 8]);
    }
    if (tid < KVBLK) Ms[tid] = rd(msk, (size_t)b * DS + kv0 + tid, dt);
  };

  stage(0);
  __syncthreads();

  // Q fragments held in regs for the whole kernel
  mfma8 bq[2];
  {
    int qrow = wave * 16 + lane16;
#pragma unroll
    for (int ks = 0; ks < 2; ++ks)
      bq[ks] = *(const mfma8*)(&Qs[qrow * 64 + (((laneq + ks * 4) ^ (qrow & 7)) << 3)]);
  }

  floatx4 acc_o[4];
#pragma unroll
  for (int d = 0; d < 4; ++d) { floatx4 z = {0.f, 0.f, 0.f, 0.f}; acc_o[d] = z; }
  float m_run = -1e30f, l_run = 0.f;

  for (int kv = 0; kv < DS / KVBLK; ++kv) {
    // ---- S^T = K @ Q^T ----
    floatx4 s[8];
#pragma unroll
    for (int t = 0; t < 8; ++t) { floatx4 z = {0.f, 0.f, 0.f, 0.f}; s[t] = z; }
#pragma unroll
    for (int ks = 0; ks < 2; ++ks)
#pragma unroll
      for (int t = 0; t < 8; ++t) {
        int krow = t * 16 + lane16;
        mfma8 a = *(const mfma8*)(&Ks[krow * 64 + (((laneq + ks * 4) ^ (krow & 7)) << 3)]);
        s[t] = __builtin_amdgcn_mfma_f32_16x16x32_bf16(a, bq[ks], s[t], 0, 0, 0);
      }
    // ---- mask+scale, online softmax (q = lane16; k = t*16+laneq*4+r) ----
    float pmax = -1e30f;
#pragma unroll
    for (int t = 0; t < 8; ++t) {
      float4 mk = *(const float4*)(&Ms[t * 16 + laneq * 4]);
#pragma unroll
      for (int r = 0; r < 4; ++r) {
        float sv = ((&mk.x)[r] == 0.f) ? -1e9f : s[t][r] * 0.125f;
        s[t][r] = sv;
        pmax = fmaxf(pmax, sv);
      }
    }
    pmax = fmaxf(pmax, __shfl_xor(pmax, 16, 64));
    pmax = fmaxf(pmax, __shfl_xor(pmax, 32, 64));
    float m_new = fmaxf(m_run, pmax);
    float scal = __expf(m_run - m_new);
    float lsum = 0.f;
#pragma unroll
    for (int t = 0; t < 8; ++t)
#pragma unroll
      for (int r = 0; r < 4; ++r) {
        float p = __expf(s[t][r] - m_new);
        s[t][r] = p;
        lsum += p;
      }
    lsum += __shfl_xor(lsum, 16, 64);
    lsum += __shfl_xor(lsum, 32, 64);
    l_run = l_run * scal + lsum;
    m_run = m_new;
    if (laneq == 0) Sx[wave][lane16] = scal;
    // ---- write P (bf16) to wave-private LDS, swizzled ----
    {
      int rowb = (wave * 16 + lane16) * 2 * KVBLK;
#pragma unroll
      for (int t = 0; t < 8; ++t) {
        int off = (t * 32 + laneq * 8) ^ ((lane16 & 7) << 4);
        union { bf16 v[4]; uint2 u; } pk;
        pk.v[0] = f2b(s[t][0]); pk.v[1] = f2b(s[t][1]);
        pk.v[2] = f2b(s[t][2]); pk.v[3] = f2b(s[t][3]);
        *(uint2*)((char*)&Ps[0] + rowb + off) = pk.u;
      }
    }
    // ---- O = O*scale + P @ V  (O rows q = laneq*4+r, cols d = dt2*16+lane16) ----
    float4 sc4 = *(const float4*)(&Sx[wave][laneq * 4]);
#pragma unroll
    for (int d = 0; d < 4; ++d)
#pragma unroll
      for (int r = 0; r < 4; ++r) acc_o[d][r] *= (&sc4.x)[r];
#pragma unroll
    for (int ks = 0; ks < 4; ++ks) {
      mfma8 pa = *(const mfma8*)((char*)&Ps[0] + (wave * 16 + lane16) * 2 * KVBLK +
                                 ((ks * 64 + laneq * 16) ^ ((lane16 & 7) << 4)));
#pragma unroll
      for (int d = 0; d < 4; ++d) {
        int drow = d * 16 + lane16;
        mfma8 vb = *(const mfma8*)((char*)&Vs[0] + drow * 2 * KVBLK +
                                   ((ks * 64 + laneq * 16) ^ ((drow & 7) << 4)));
        acc_o[d] = __builtin_amdgcn_mfma_f32_16x16x32_bf16(pa, vb, acc_o[d], 0, 0, 0);
      }
    }
    __syncthreads();  // all waves done reading Ks/Vs
    if (kv + 1 < DS / KVBLK) {
      stage((kv + 1) * KVBLK);
      __syncthreads();
    }
  }

  // epilogue: O /= l ; store to ao[b, q, h*64+d]
  if (laneq == 0) Sx[wave][lane16] = l_run;
  float4 l4 = *(const float4*)(&Sx[wave][laneq * 4]);
#pragma unroll
  for (int r = 0; r < 4; ++r) {
    float inv = 1.f / (&l4.x)[r];
    int q = q0 + wave * 16 + laneq * 4 + r;
    size_t base = ((size_t)b * DS + q) * DD + h * 64;
#pragma unroll
    for (int d = 0; d < 4; ++d) ao[base + d * 16 + lane16] = f2b(acc_o[d][r] * inv);
  }
}

enum { EPI_BF16 = 0, EPI_BIAS_RELU = 1, EPI_ACC_ATOMIC = 2, EPI_SCORES = 3 };

// aux indexed at [aoff + col] with dtype flag
// 3-buffer counted-vmcnt pipeline (T4): per K-step, wait vmcnt(4) (NOT 0) so the
// next tile's 4 global_load_lds stay in flight across the raw barrier; stage is
// issued AFTER the barrier (buffer it overwrites was last ds_read the previous
// iteration -> no race). Only the final iteration drains to vmcnt(0).
template <int NT, int WM_, int WN_, int TM, int TN, int EPI>
__global__ __launch_bounds__(256) void gemm_bt(
    const bf16* __restrict__ A, int lda, long long zsa,
    const bf16* __restrict__ Bt, int ldb, long long zsb,
    void* __restrict__ C, int ldc, long long zsc,
    int K, const void* __restrict__ aux, long long aoff, float scale,
    const int* __restrict__ dflag) {
  constexpr int MT = 128, BK = 32;
  constexpr int SM = MT / WM_, SN = NT / WN_;
  constexpr int nsA = (MT * BK / 8) / 256;
  constexpr int nsB = (NT * BK / 8) / 256;
  __shared__ __align__(16) bf16 As[3][MT * BK];
  __shared__ __align__(16) bf16 Bs[3][NT * BK];
  const int tid = threadIdx.x;
  const int lane = tid & 63, wave = tid >> 6;
  const int lane16 = lane & 15, laneq = lane >> 4;
  const int wm = wave / WN_, wn = wave % WN_;
  const int dt = dflag[0];
  const long long z = blockIdx.z;
  A += z * zsa;
  Bt += z * zsb;
  const int m0 = blockIdx.x * MT, n0 = blockIdx.y * NT;

  floatx4 acc[TM][TN];
#pragma unroll
  for (int i = 0; i < TM; ++i)
#pragma unroll
    for (int j = 0; j < TN; ++j) {
      floatx4 zz = {0.f, 0.f, 0.f, 0.f};
      acc[i][j] = zz;
    }

  // async staging into buffer `buf` for K-offset k0 (4 gld_lds = 4 vmcnt units)
  auto stage = [&](int buf, int k0) {
#pragma unroll
    for (int i = 0; i < nsA; ++i) {
      int c = tid + i * 256;
      int row = c >> 2, kk = (c & 3) << 3;
      gld_lds16(A + (size_t)(m0 + row) * lda + k0 + kk,
                &As[buf][(size_t)(wave * 64 + i * 256) * 8]);
    }
#pragma unroll
    for (int i = 0; i < nsB; ++i) {
      int c = tid + i * 256;
      int row = c >> 2, kk = (c & 3) << 3;
      gld_lds16(Bt + (size_t)(n0 + row) * ldb + k0 + kk,
                &Bs[buf][(size_t)(wave * 64 + i * 256) * 8]);
    }
  };

  const int NS = K / BK;
  stage(0, 0);
  if (NS > 1) stage(1, BK);

  int cur = 0;
  for (int i = 0; i < NS; ++i) {
    // buf cur's 4 loads are the oldest outstanding group; vmcnt(4) retires them
    // while buf (cur+1)'s 4 stay in flight across the barrier (never-drain).
    if (i + 1 < NS) {
      asm volatile("s_waitcnt vmcnt(4)" ::: "memory");
    } else {
      asm volatile("s_waitcnt vmcnt(0)" ::: "memory");
    }
    __builtin_amdgcn_s_barrier();
    __builtin_amdgcn_sched_barrier(0);
    if (i + 2 < NS) {
      int nb = cur - 1; if (nb < 0) nb = 2;  // (cur+2)%3: overwrites buf read at iter i-1
      stage(nb, (i + 2) * BK);
    }
    mfma8 af[TM], bfr[TN];
#pragma unroll
    for (int t = 0; t < TM; ++t)
      af[t] = *(const mfma8*)(&As[cur][(wm * SM + t * 16 + lane16) * BK + laneq * 8]);
#pragma unroll
    for (int j = 0; j < TN; ++j)
      bfr[j] = *(const mfma8*)(&Bs[cur][(wn * SN + j * 16 + lane16) * BK + laneq * 8]);
#pragma unroll
    for (int t = 0; t < TM; ++t)
#pragma unroll
      for (int j = 0; j < TN; ++j)
        acc[t][j] = __builtin_amdgcn_mfma_f32_16x16x32_bf16(af[t], bfr[j], acc[t][j], 0, 0, 0);
    cur = (cur == 2) ? 0 : cur + 1;
  }

#pragma unroll
  for (int i = 0; i < TM; ++i) {
    const int rb = m0 + wm * SM + i * 16 + laneq * 4;
#pragma unroll
    for (int j = 0; j < TN; ++j) {
      const int col = n0 + wn * SN + j * 16 + lane16;
#pragma unroll
      for (int r = 0; r < 4; ++r) {
        const size_t idx = (size_t)(rb + r) * ldc + col;
        float v = acc[i][j][r];
        if constexpr (EPI == EPI_BF16) {
          ((bf16*)C)[(size_t)(z * zsc) + idx] = f2b(v);
        } else if constexpr (EPI == EPI_BIAS_RELU) {
          v += rd(aux, (size_t)(aoff + col), dt);
          ((bf16*)C)[idx] = f2b(fmaxf(v, 0.f));
        } else if constexpr (EPI == EPI_ACC_ATOMIC) {
          if (z == 0) v += rd(aux, (size_t)(aoff + col), dt);
          atomicAdd((float*)C + idx, v);
        } else {
          v *= scale;
          if (rd(aux, (size_t)(aoff + col), dt) == 0.f) v = -1e9f;
          ((float*)C)[(size_t)(z * zsc) + idx] = v;
        }
      }
    }
  }
}

extern "C" void kernel_launch(void* const* d_in, const int* in_sizes, int n_in,
                              void* d_out, int out_size, void* d_ws, size_t ws_size,
                              hipStream_t stream) {
  const int* ids   = (const int*)d_in[0];
  const void* msk  = d_in[1];
  const void* emb  = d_in[2];
  const void* pe   = d_in[3];
  const void* w_q  = d_in[4];
  const void* w_k  = d_in[5];
  const void* w_v  = d_in[6];
  const void* w_o  = d_in[7];
  const void* b_o  = d_in[8];
  const void* w1   = d_in[9];
  const void* b1   = d_in[10];
  const void* w2   = d_in[11];
  const void* b2   = d_in[12];
  const void* ln1s = d_in[13];
  const void* ln1b = d_in[14];
  const void* ln2s = d_in[15];
  const void* ln2b = d_in[16];
  const void* lnfs = d_in[17];
  const void* lnfb = d_in[18];

  char* ws = (char*)d_ws;
  float* x   = (float*)(ws + 0);          // 8 MB
  bf16* qkv  = (bf16*)(ws + 8388608);     // 12 MB
  bf16* h    = (bf16*)(ws + 20971520);    // 4 MB
  bf16* ao   = (bf16*)(ws + 25165824);    // 4 MB
  bf16* vt   = (bf16*)(ws + 29360128);    // 4 MB
  bf16* mid  = (bf16*)(ws + 33554432);    // 16 MB
  bf16* wT   = (bf16*)(ws + 50331648);    // 8 MB
  int* flag  = (int*)(ws + 58720256);     // 4 KB slot

  dim3 blk(256);
  detect_dtype<<<1, 64, 0, stream>>>((const unsigned*)msk, flag);
  embed_kernel<<<DB * DS, blk, 0, stream>>>(ids, emb, pe, flag, x);

  for (int l = 0; l < DL; ++l) {
    const long long lo = (long long)l * DD;        // LN/bias element offset
    const long long lw = (long long)l * DD;        // weight row offset ([L*R, C])

    ln_kernel<<<DB * DS, blk, 0, stream>>>(x, ln1s, ln1b, lo, flag, h, 0);

    transpose_any<<<dim3(32, 32), blk, 0, stream>>>(w_q, lw, wT, DD, DD, flag);
    transpose_any<<<dim3(32, 32), blk, 0, stream>>>(w_k, lw, wT + DD * DD, DD, DD, flag);
    transpose_any<<<dim3(32, 32), blk, 0, stream>>>(w_v, lw, wT + 2 * DD * DD, DD, DD, flag);
    gemm_bt<128, 2, 2, 4, 4, EPI_BF16><<<dim3(16, 24, 1), blk, 0, stream>>>(
        h, DD, 0, wT, DD, 0, qkv, 3072, 0, DD, nullptr, 0, 1.f, flag);

    vtrans_kernel<<<dim3(32, 2, 32), blk, 0, stream>>>(qkv, vt);
    flash_attn<<<dim3(DS / 64, DB * DH), blk, 0, stream>>>(qkv, vt, msk, flag, ao);

    transpose_any<<<dim3(32, 32), blk, 0, stream>>>(w_o, lw, wT, DD, DD, flag);
    gemm_bt<128, 2, 2, 4, 4, EPI_ACC_ATOMIC><<<dim3(16, 8, 2), blk, 0, stream>>>(
        ao, DD, 512, wT, DD, 512, x, DD, 0, 512, b_o, lo, 1.f, flag);

    ln_kernel<<<DB * DS, blk, 0, stream>>>(x, ln2s, ln2b, lo, flag, h, 0);

    transpose_any<<<dim3(128, 32), blk, 0, stream>>>(w1, lw, wT, DD, DF, flag);
    gemm_bt<128, 2, 2, 4, 4, EPI_BIAS_RELU><<<dim3(16, 32, 1), blk, 0, stream>>>(
        h, DD, 0, wT, DD, 0, mid, DF, 0, DD, b1, (long long)l * DF, 1.f, flag);

    transpose_any<<<dim3(32, 128), blk, 0, stream>>>(w2, (long long)l * DF, wT, DF, DD, flag);
    gemm_bt<128, 2, 2, 4, 4, EPI_ACC_ATOMIC><<<dim3(16, 8, 2), blk, 0, stream>>>(
        mid, DF, 2048, wT, DF, 2048, x, DD, 0, 2048, b2, lo, 1.f, flag);
  }

  ln_kernel<<<DB * DS, blk, 0, stream>>>(x, lnfs, lnfb, 0, flag, d_out, 1);
}

// Round 6
// 1770.291 us; speedup vs baseline: 1.0059x; 1.0059x over previous
//
#include <hip/hip_runtime.h>
#include <hip/hip_bf16.h>

#define DL 6
#define DD 1024
#define DH 16
#define DF 4096
#define DB 2
#define DS 1024
#define DDK 64

typedef __hip_bfloat16 bf16;
typedef short mfma_t;
typedef mfma_t mfma8 __attribute__((ext_vector_type(8)));
typedef float floatx4 __attribute__((ext_vector_type(4)));

__device__ __forceinline__ float b2f(bf16 v) { return __bfloat162float(v); }
__device__ __forceinline__ bf16 f2b(float v) { return __float2bfloat16(v); }
__device__ __forceinline__ float rd(const void* p, size_t i, int dt) {
  return dt ? b2f(((const bf16*)p)[i]) : ((const float*)p)[i];
}

// async global->LDS, 16B per lane; LDS dest = wave-uniform base + lane*16
__device__ __forceinline__ void gld_lds16(const bf16* g, bf16* l) {
  __builtin_amdgcn_global_load_lds(
      (const __attribute__((address_space(1))) unsigned int*)g,
      (__attribute__((address_space(3))) unsigned int*)l, 16, 0, 0);
}

__global__ void detect_dtype(const unsigned* __restrict__ msk, int* __restrict__ flag) {
  if (threadIdx.x == 0) flag[0] = (msk[0] == 0x3F800000u) ? 0 : 1;
}

template <int OP>
__device__ __forceinline__ float block_reduce(float v, float* sm) {
#pragma unroll
  for (int off = 32; off > 0; off >>= 1) {
    float o = __shfl_down(v, off, 64);
    v = OP ? fmaxf(v, o) : v + o;
  }
  if ((threadIdx.x & 63) == 0) sm[threadIdx.x >> 6] = v;
  __syncthreads();
  float r = OP ? fmaxf(fmaxf(sm[0], sm[1]), fmaxf(sm[2], sm[3]))
               : (sm[0] + sm[1]) + (sm[2] + sm[3]);
  __syncthreads();
  return r;
}

__global__ __launch_bounds__(256) void embed_kernel(const int* __restrict__ ids,
                                                    const void* __restrict__ emb,
                                                    const void* __restrict__ pe,
                                                    const int* __restrict__ dflag,
                                                    float* __restrict__ x) {
  const int dt = dflag[0];
  int t = blockIdx.x;
  int id = ids[t];
  int s = t & (DS - 1);
  int c = threadIdx.x * 4;
  float* xo = x + (size_t)t * DD + c;
#pragma unroll
  for (int i = 0; i < 4; ++i)
    xo[i] = rd(emb, (size_t)id * DD + c + i, dt) * 32.0f + rd(pe, (size_t)s * DD + c + i, dt);
}

// s,b indexed at [poff + c]; poff = layer element offset (dtype-independent count)
__global__ __launch_bounds__(256) void ln_kernel(const float* __restrict__ x,
                                                 const void* __restrict__ s,
                                                 const void* __restrict__ b,
                                                 long long poff,
                                                 const int* __restrict__ dflag,
                                                 void* __restrict__ out, int is_final) {
  __shared__ float sm[4];
  const int dt = dflag[0];
  int row = blockIdx.x;
  const float4* xr = (const float4*)(x + (size_t)row * DD);
  float4 v = xr[threadIdx.x];
  float sum = block_reduce<0>(v.x + v.y + v.z + v.w, sm);
  float mean = sum * (1.0f / DD);
  float dx = v.x - mean, dy = v.y - mean, dz = v.z - mean, dw = v.w - mean;
  float ss = block_reduce<0>(dx * dx + dy * dy + dz * dz + dw * dw, sm);
  float rstd = rsqrtf(ss * (1.0f / DD) + 1e-6f);
  int c = threadIdx.x * 4;
  size_t p = (size_t)poff + c;
  float o0 = dx * rstd * rd(s, p + 0, dt) + rd(b, p + 0, dt);
  float o1 = dy * rstd * rd(s, p + 1, dt) + rd(b, p + 1, dt);
  float o2 = dz * rstd * rd(s, p + 2, dt) + rd(b, p + 2, dt);
  float o3 = dw * rstd * rd(s, p + 3, dt) + rd(b, p + 3, dt);
  if (is_final && dt == 0) {
    float* o = (float*)out + (size_t)row * DD + c;
    o[0] = o0; o[1] = o1; o[2] = o2; o[3] = o3;
  } else {
    bf16* o = (bf16*)out + (size_t)row * DD + c;
    o[0] = f2b(o0); o[1] = f2b(o1); o[2] = f2b(o2); o[3] = f2b(o3);
  }
}

// Batched transpose of the 4 square per-layer weights.
// z = l*4 + which (0=wq 1=wk 2=wv 3=wo); out[z] = W_l^T [DD][DD].
__global__ __launch_bounds__(256) void transpose_sq(const void* __restrict__ w_q,
                                                    const void* __restrict__ w_k,
                                                    const void* __restrict__ w_v,
                                                    const void* __restrict__ w_o,
                                                    bf16* __restrict__ out,
                                                    const int* __restrict__ dflag) {
  __shared__ bf16 t[32][33];
  const int dt = dflag[0];
  const int z = blockIdx.z, l = z >> 2, which = z & 3;
  const void* in = which == 0 ? w_q : which == 1 ? w_k : which == 2 ? w_v : w_o;
  const long long row_off = (long long)l * DD;
  bf16* o = out + (size_t)z * DD * DD;
  int c0 = blockIdx.x * 32, r0 = blockIdx.y * 32;
  int tx = threadIdx.x & 31, ty = threadIdx.x >> 5;
#pragma unroll
  for (int i = 0; i < 4; ++i) {
    int r = ty + i * 8;
    size_t idx = (size_t)(row_off + r0 + r) * DD + c0 + tx;
    t[r][tx] = dt ? ((const bf16*)in)[idx] : f2b(((const float*)in)[idx]);
  }
  __syncthreads();
#pragma unroll
  for (int i = 0; i < 4; ++i) {
    int r = ty + i * 8;
    o[(size_t)(c0 + r) * DD + r0 + tx] = t[tx][r];
  }
}

// Batched rectangular transpose: z = layer; in rows = R (per layer), cols = C.
// out[z] = [C][R].
__global__ __launch_bounds__(256) void transpose_rect(const void* __restrict__ in,
                                                      bf16* __restrict__ out,
                                                      int R, int C,
                                                      const int* __restrict__ dflag) {
  __shared__ bf16 t[32][33];
  const int dt = dflag[0];
  const int l = blockIdx.z;
  const long long row_off = (long long)l * R;
  bf16* o = out + (size_t)l * R * C;
  int c0 = blockIdx.x * 32, r0 = blockIdx.y * 32;
  int tx = threadIdx.x & 31, ty = threadIdx.x >> 5;
#pragma unroll
  for (int i = 0; i < 4; ++i) {
    int r = ty + i * 8;
    size_t idx = (size_t)(row_off + r0 + r) * C + c0 + tx;
    t[r][tx] = dt ? ((const bf16*)in)[idx] : f2b(((const float*)in)[idx]);
  }
  __syncthreads();
#pragma unroll
  for (int i = 0; i < 4; ++i) {
    int r = ty + i * 8;
    o[(size_t)(c0 + r) * R + r0 + tx] = t[tx][r];
  }
}

__global__ __launch_bounds__(256) void vtrans_kernel(const bf16* __restrict__ qkv,
                                                     bf16* __restrict__ vt) {
  __shared__ bf16 t[32][33];
  int bh = blockIdx.z;
  const bf16* src = qkv + (size_t)(bh >> 4) * DS * 3072 + 2048 + (bh & 15) * DDK;
  bf16* dst = vt + (size_t)bh * DDK * DS;
  int s0 = blockIdx.x * 32, d0 = blockIdx.y * 32;
  int tx = threadIdx.x & 31, ty = threadIdx.x >> 5;
#pragma unroll
  for (int i = 0; i < 4; ++i) {
    int r = ty + i * 8;
    t[r][tx] = src[(size_t)(s0 + r) * 3072 + d0 + tx];
  }
  __syncthreads();
#pragma unroll
  for (int i = 0; i < 4; ++i) {
    int r = ty + i * 8;
    dst[(size_t)(d0 + r) * DS + s0 + tx] = t[tx][r];
  }
}

// ---------------- fused flash attention ----------------
// grid (DS/64, DB*DH); 4 waves; wave w owns q-rows [w*16, w*16+16).
// Swapped QK^T: S^T tile = mfma(A=K_rows, B=Q_rows) -> lane16 = q, laneq*4+r = k.
// K/Q/V staged via global_load_lds with pre-swizzled SOURCE (XOR (row&7)<<4 on
// 16B slots); ds_read applies the same XOR -> 2-way bank aliasing (free).
#define KVBLK 128
__global__ __launch_bounds__(256) void flash_attn(const bf16* __restrict__ qkv,
                                                  const bf16* __restrict__ vt,
                                                  const void* __restrict__ msk,
                                                  const int* __restrict__ dflag,
                                                  bf16* __restrict__ ao) {
  __shared__ __align__(16) bf16 Qs[64 * 64];         // [q][d]   8 KB
  __shared__ __align__(16) bf16 Ks[KVBLK * 64];      // [k][d]  16 KB
  __shared__ __align__(16) bf16 Vs[64 * KVBLK];      // [d][k]  16 KB (from vt)
  __shared__ __align__(16) bf16 Ps[4 * 16 * KVBLK];  // per-wave P 16 KB
  __shared__ float Ms[KVBLK];
  __shared__ float Sx[4][16];

  const int tid = threadIdx.x;
  const int lane = tid & 63, wave = tid >> 6;
  const int lane16 = lane & 15, laneq = lane >> 4;
  const int dt = dflag[0];
  const int qt = blockIdx.x, bh = blockIdx.y;
  const int b = bh >> 4, h = bh & 15;
  const int q0 = qt * 64;

  const bf16* Qg = qkv + (size_t)b * DS * 3072 + (size_t)q0 * 3072 + h * 64;
  const bf16* Kg = qkv + (size_t)b * DS * 3072 + 1024 + h * 64;
  const bf16* Vg = vt + (size_t)bh * DDK * DS;

  // stage Q once: 64 rows x 8 slots(16B)
#pragma unroll
  for (int i = 0; i < 2; ++i) {
    int c = tid + i * 256;
    int row = c >> 3, sl = c & 7;
    gld_lds16(Qg + (size_t)row * 3072 + ((sl ^ (row & 7)) << 3), &Qs[c * 8]);
  }
  // stage K,V,mask for tile kv0
  auto stage = [&](int kv0) {
#pragma unroll
    for (int i = 0; i < 4; ++i) {
      int c = tid + i * 256;
      int row = c >> 3, sl = c & 7;
      gld_lds16(Kg + (size_t)(kv0 + row) * 3072 + ((sl ^ (row & 7)) << 3), &Ks[c * 8]);
    }
#pragma unroll
    for (int i = 0; i < 4; ++i) {
      int c = tid + i * 256;
      int row = c >> 4, sl = c & 15;
      gld_lds16(Vg + (size_t)row * DS + kv0 + ((sl ^ (row & 7)) << 3), &Vs[c * 8]);
    }
    if (tid < KVBLK) Ms[tid] = rd(msk, (size_t)b * DS + kv0 + tid, dt);
  };

  stage(0);
  __syncthreads();

  // Q fragments held in regs for the whole kernel
  mfma8 bq[2];
  {
    int qrow = wave * 16 + lane16;
#pragma unroll
    for (int ks = 0; ks < 2; ++ks)
      bq[ks] = *(const mfma8*)(&Qs[qrow * 64 + (((laneq + ks * 4) ^ (qrow & 7)) << 3)]);
  }

  floatx4 acc_o[4];
#pragma unroll
  for (int d = 0; d < 4; ++d) { floatx4 z = {0.f, 0.f, 0.f, 0.f}; acc_o[d] = z; }
  float m_run = -1e30f, l_run = 0.f;

  for (int kv = 0; kv < DS / KVBLK; ++kv) {
    // ---- S^T = K @ Q^T ----
    floatx4 s[8];
#pragma unroll
    for (int t = 0; t < 8; ++t) { floatx4 z = {0.f, 0.f, 0.f, 0.f}; s[t] = z; }
    __builtin_amdgcn_s_setprio(1);
#pragma unroll
    for (int ks = 0; ks < 2; ++ks)
#pragma unroll
      for (int t = 0; t < 8; ++t) {
        int krow = t * 16 + lane16;
        mfma8 a = *(const mfma8*)(&Ks[krow * 64 + (((laneq + ks * 4) ^ (krow & 7)) << 3)]);
        s[t] = __builtin_amdgcn_mfma_f32_16x16x32_bf16(a, bq[ks], s[t], 0, 0, 0);
      }
    __builtin_amdgcn_s_setprio(0);
    // ---- mask+scale, online softmax (q = lane16; k = t*16+laneq*4+r) ----
    float pmax = -1e30f;
#pragma unroll
    for (int t = 0; t < 8; ++t) {
      float4 mk = *(const float4*)(&Ms[t * 16 + laneq * 4]);
#pragma unroll
      for (int r = 0; r < 4; ++r) {
        float sv = ((&mk.x)[r] == 0.f) ? -1e9f : s[t][r] * 0.125f;
        s[t][r] = sv;
        pmax = fmaxf(pmax, sv);
      }
    }
    pmax = fmaxf(pmax, __shfl_xor(pmax, 16, 64));
    pmax = fmaxf(pmax, __shfl_xor(pmax, 32, 64));
    float m_new = fmaxf(m_run, pmax);
    float scal = __expf(m_run - m_new);
    float lsum = 0.f;
#pragma unroll
    for (int t = 0; t < 8; ++t)
#pragma unroll
      for (int r = 0; r < 4; ++r) {
        float p = __expf(s[t][r] - m_new);
        s[t][r] = p;
        lsum += p;
      }
    lsum += __shfl_xor(lsum, 16, 64);
    lsum += __shfl_xor(lsum, 32, 64);
    l_run = l_run * scal + lsum;
    m_run = m_new;
    if (laneq == 0) Sx[wave][lane16] = scal;
    // ---- write P (bf16) to wave-private LDS, swizzled ----
    {
      int rowb = (wave * 16 + lane16) * 2 * KVBLK;
#pragma unroll
      for (int t = 0; t < 8; ++t) {
        int off = (t * 32 + laneq * 8) ^ ((lane16 & 7) << 4);
        union { bf16 v[4]; uint2 u; } pk;
        pk.v[0] = f2b(s[t][0]); pk.v[1] = f2b(s[t][1]);
        pk.v[2] = f2b(s[t][2]); pk.v[3] = f2b(s[t][3]);
        *(uint2*)((char*)&Ps[0] + rowb + off) = pk.u;
      }
    }
    // ---- O = O*scale + P @ V  (O rows q = laneq*4+r, cols d = dt2*16+lane16) ----
    float4 sc4 = *(const float4*)(&Sx[wave][laneq * 4]);
#pragma unroll
    for (int d = 0; d < 4; ++d)
#pragma unroll
      for (int r = 0; r < 4; ++r) acc_o[d][r] *= (&sc4.x)[r];
    __builtin_amdgcn_s_setprio(1);
#pragma unroll
    for (int ks = 0; ks < 4; ++ks) {
      mfma8 pa = *(const mfma8*)((char*)&Ps[0] + (wave * 16 + lane16) * 2 * KVBLK +
                                 ((ks * 64 + laneq * 16) ^ ((lane16 & 7) << 4)));
#pragma unroll
      for (int d = 0; d < 4; ++d) {
        int drow = d * 16 + lane16;
        mfma8 vb = *(const mfma8*)((char*)&Vs[0] + drow * 2 * KVBLK +
                                   ((ks * 64 + laneq * 16) ^ ((drow & 7) << 4)));
        acc_o[d] = __builtin_amdgcn_mfma_f32_16x16x32_bf16(pa, vb, acc_o[d], 0, 0, 0);
      }
    }
    __builtin_amdgcn_s_setprio(0);
    __syncthreads();  // all waves done reading Ks/Vs
    if (kv + 1 < DS / KVBLK) {
      stage((kv + 1) * KVBLK);
      __syncthreads();
    }
  }

  // epilogue: O /= l ; store to ao[b, q, h*64+d]
  if (laneq == 0) Sx[wave][lane16] = l_run;
  float4 l4 = *(const float4*)(&Sx[wave][laneq * 4]);
#pragma unroll
  for (int r = 0; r < 4; ++r) {
    float inv = 1.f / (&l4.x)[r];
    int q = q0 + wave * 16 + laneq * 4 + r;
    size_t base = ((size_t)b * DS + q) * DD + h * 64;
#pragma unroll
    for (int d = 0; d < 4; ++d) ao[base + d * 16 + lane16] = f2b(acc_o[d][r] * inv);
  }
}

enum { EPI_BF16 = 0, EPI_BIAS_RELU = 1, EPI_ACC_ATOMIC = 2, EPI_SCORES = 3 };

// aux indexed at [aoff + col] with dtype flag
// 2-phase double-buffered pipeline: stage tile t+1 into buf[cur^1] BEFORE
// ds_read+MFMA of buf[cur]; single barrier per K-step (T3-minimum recipe).
template <int NT, int WM_, int WN_, int TM, int TN, int EPI>
__global__ __launch_bounds__(256) void gemm_bt(
    const bf16* __restrict__ A, int lda, long long zsa,
    const bf16* __restrict__ Bt, int ldb, long long zsb,
    void* __restrict__ C, int ldc, long long zsc,
    int K, const void* __restrict__ aux, long long aoff, float scale,
    const int* __restrict__ dflag) {
  constexpr int MT = 128, BK = 32;
  constexpr int SM = MT / WM_, SN = NT / WN_;
  constexpr int nsA = (MT * BK / 8) / 256;
  constexpr int nsB = (NT * BK / 8) / 256;
  __shared__ __align__(16) bf16 As[2][MT * BK];
  __shared__ __align__(16) bf16 Bs[2][NT * BK];
  const int tid = threadIdx.x;
  const int lane = tid & 63, wave = tid >> 6;
  const int lane16 = lane & 15, laneq = lane >> 4;
  const int wm = wave / WN_, wn = wave % WN_;
  const int dt = dflag[0];
  const long long z = blockIdx.z;
  A += z * zsa;
  Bt += z * zsb;
  const int m0 = blockIdx.x * MT, n0 = blockIdx.y * NT;

  floatx4 acc[TM][TN];
#pragma unroll
  for (int i = 0; i < TM; ++i)
#pragma unroll
    for (int j = 0; j < TN; ++j) {
      floatx4 zz = {0.f, 0.f, 0.f, 0.f};
      acc[i][j] = zz;
    }

  // async staging into buffer `buf` for K-offset k0
  auto stage = [&](int buf, int k0) {
#pragma unroll
    for (int i = 0; i < nsA; ++i) {
      int c = tid + i * 256;
      int row = c >> 2, kk = (c & 3) << 3;
      gld_lds16(A + (size_t)(m0 + row) * lda + k0 + kk,
                &As[buf][(size_t)(wave * 64 + i * 256) * 8]);
    }
#pragma unroll
    for (int i = 0; i < nsB; ++i) {
      int c = tid + i * 256;
      int row = c >> 2, kk = (c & 3) << 3;
      gld_lds16(Bt + (size_t)(n0 + row) * ldb + k0 + kk,
                &Bs[buf][(size_t)(wave * 64 + i * 256) * 8]);
    }
  };

  stage(0, 0);
  __syncthreads();  // drains vmcnt(0): buf0 ready

  int cur = 0;
  for (int k0 = 0; k0 < K; k0 += BK, cur ^= 1) {
    if (k0 + BK < K) stage(cur ^ 1, k0 + BK);  // prefetch next tile
    mfma8 af[TM], bfr[TN];
#pragma unroll
    for (int i = 0; i < TM; ++i)
      af[i] = *(const mfma8*)(&As[cur][(wm * SM + i * 16 + lane16) * BK + laneq * 8]);
#pragma unroll
    for (int j = 0; j < TN; ++j)
      bfr[j] = *(const mfma8*)(&Bs[cur][(wn * SN + j * 16 + lane16) * BK + laneq * 8]);
#pragma unroll
    for (int i = 0; i < TM; ++i)
#pragma unroll
      for (int j = 0; j < TN; ++j)
        acc[i][j] = __builtin_amdgcn_mfma_f32_16x16x32_bf16(af[i], bfr[j], acc[i][j], 0, 0, 0);
    __syncthreads();  // next buffer staged, this one free
  }

#pragma unroll
  for (int i = 0; i < TM; ++i) {
    const int rb = m0 + wm * SM + i * 16 + laneq * 4;
#pragma unroll
    for (int j = 0; j < TN; ++j) {
      const int col = n0 + wn * SN + j * 16 + lane16;
#pragma unroll
      for (int r = 0; r < 4; ++r) {
        const size_t idx = (size_t)(rb + r) * ldc + col;
        float v = acc[i][j][r];
        if constexpr (EPI == EPI_BF16) {
          ((bf16*)C)[(size_t)(z * zsc) + idx] = f2b(v);
        } else if constexpr (EPI == EPI_BIAS_RELU) {
          v += rd(aux, (size_t)(aoff + col), dt);
          ((bf16*)C)[idx] = f2b(fmaxf(v, 0.f));
        } else if constexpr (EPI == EPI_ACC_ATOMIC) {
          if (z == 0) v += rd(aux, (size_t)(aoff + col), dt);
          atomicAdd((float*)C + idx, v);
        } else {
          v *= scale;
          if (rd(aux, (size_t)(aoff + col), dt) == 0.f) v = -1e9f;
          ((float*)C)[(size_t)(z * zsc) + idx] = v;
        }
      }
    }
  }
}

extern "C" void kernel_launch(void* const* d_in, const int* in_sizes, int n_in,
                              void* d_out, int out_size, void* d_ws, size_t ws_size,
                              hipStream_t stream) {
  const int* ids   = (const int*)d_in[0];
  const void* msk  = d_in[1];
  const void* emb  = d_in[2];
  const void* pe   = d_in[3];
  const void* w_q  = d_in[4];
  const void* w_k  = d_in[5];
  const void* w_v  = d_in[6];
  const void* w_o  = d_in[7];
  const void* b_o  = d_in[8];
  const void* w1   = d_in[9];
  const void* b1   = d_in[10];
  const void* w2   = d_in[11];
  const void* b2   = d_in[12];
  const void* ln1s = d_in[13];
  const void* ln1b = d_in[14];
  const void* ln2s = d_in[15];
  const void* ln2b = d_in[16];
  const void* lnfs = d_in[17];
  const void* lnfb = d_in[18];

  char* ws = (char*)d_ws;
  float* x   = (float*)(ws + 0);                    // 8 MB
  bf16* qkv  = (bf16*)(ws + (8u << 20));            // 12 MB
  bf16* h    = (bf16*)(ws + (20u << 20));           // 4 MB
  bf16* ao   = (bf16*)(ws + (24u << 20));           // 4 MB
  bf16* vt   = (bf16*)(ws + (28u << 20));           // 4 MB
  bf16* mid  = (bf16*)(ws + (32u << 20));           // 16 MB
  int* flag  = (int*)(ws + (48u << 20));            // 4 KB
  // all-layer transposed weights: squares [L][4][DD][DD] (48 MB),
  // w1T [L][DF][DD] (48 MB), w2T [L][DD][DF] (48 MB)
  bf16* wTsq = (bf16*)(ws + (64u << 20));
  bf16* w1T  = (bf16*)(ws + (112u << 20));
  bf16* w2T  = (bf16*)(ws + (160u << 20));

  dim3 blk(256);
  detect_dtype<<<1, 64, 0, stream>>>((const unsigned*)msk, flag);

  // all weight transposes, hoisted out of the layer loop (3 dispatches)
  transpose_sq<<<dim3(32, 32, DL * 4), blk, 0, stream>>>(w_q, w_k, w_v, w_o, wTsq, flag);
  transpose_rect<<<dim3(128, 32, DL), blk, 0, stream>>>(w1, w1T, DD, DF, flag);
  transpose_rect<<<dim3(32, 128, DL), blk, 0, stream>>>(w2, w2T, DF, DD, flag);

  embed_kernel<<<DB * DS, blk, 0, stream>>>(ids, emb, pe, flag, x);

  for (int l = 0; l < DL; ++l) {
    const long long lo = (long long)l * DD;  // LN/bias element offset
    bf16* wq_l = wTsq + (size_t)(l * 4) * DD * DD;      // [wq^T][wk^T][wv^T] stacked
    bf16* wo_l = wTsq + (size_t)(l * 4 + 3) * DD * DD;
    bf16* w1_l = w1T + (size_t)l * DF * DD;
    bf16* w2_l = w2T + (size_t)l * DD * DF;

    ln_kernel<<<DB * DS, blk, 0, stream>>>(x, ln1s, ln1b, lo, flag, h, 0);

    gemm_bt<128, 2, 2, 4, 4, EPI_BF16><<<dim3(16, 24, 1), blk, 0, stream>>>(
        h, DD, 0, wq_l, DD, 0, qkv, 3072, 0, DD, nullptr, 0, 1.f, flag);

    vtrans_kernel<<<dim3(32, 2, 32), blk, 0, stream>>>(qkv, vt);
    flash_attn<<<dim3(DS / 64, DB * DH), blk, 0, stream>>>(qkv, vt, msk, flag, ao);

    gemm_bt<128, 2, 2, 4, 4, EPI_ACC_ATOMIC><<<dim3(16, 8, 4), blk, 0, stream>>>(
        ao, DD, 256, wo_l, DD, 256, x, DD, 0, 256, b_o, lo, 1.f, flag);

    ln_kernel<<<DB * DS, blk, 0, stream>>>(x, ln2s, ln2b, lo, flag, h, 0);

    gemm_bt<128, 2, 2, 4, 4, EPI_BIAS_RELU><<<dim3(16, 32, 1), blk, 0, stream>>>(
        h, DD, 0, w1_l, DD, 0, mid, DF, 0, DD, b1, (long long)l * DF, 1.f, flag);

    gemm_bt<128, 2, 2, 4, 4, EPI_ACC_ATOMIC><<<dim3(16, 8, 4), blk, 0, stream>>>(
        mid, DF, 1024, w2_l, DF, 1024, x, DD, 0, 1024, b2, lo, 1.f, flag);
  }

  ln_kernel<<<DB * DS, blk, 0, stream>>>(x, lnfs, lnfb, 0, flag, d_out, 1);
}